// Round 1
// baseline (197.964 us; speedup 1.0000x reference)
//
#include <hip/hip_runtime.h>
#include <stdint.h>

#define SL 4096
#define DM 1024
#define NH 16
#define HDIM 64

typedef short short8 __attribute__((ext_vector_type(8)));
typedef float f32x4 __attribute__((ext_vector_type(4)));

__device__ __forceinline__ unsigned short f2bf(float f) {
  unsigned int u = __float_as_uint(f);
  u += 0x7FFF + ((u >> 16) & 1);
  return (unsigned short)(u >> 16);
}

__device__ __forceinline__ void gload_lds16(const void* g, void* l) {
  __builtin_amdgcn_global_load_lds((const __attribute__((address_space(1))) void*)g,
                                   (__attribute__((address_space(3))) void*)l, 16, 0, 0);
}

// ---------------- cast fp32 -> bf16, 4 elems/thread ----------------
__global__ void cast4(const float* __restrict__ src, unsigned short* __restrict__ dst, int n4) {
  int i = blockIdx.x * blockDim.x + threadIdx.x;
  if (i >= n4) return;
  float4 v = ((const float4*)src)[i];
  ushort4 o = make_ushort4(f2bf(v.x), f2bf(v.y), f2bf(v.z), f2bf(v.w));
  ((ushort4*)dst)[i] = o;
}

// ---------------- bf16 MFMA GEMM: C[M,N] = A[M,K] * B[N,K]^T (fp32 out) ----
// m97 structure: 128x128 tile, BK=32, 4 waves (2x2 of 64x64), global_load_lds.
__global__ void gemm_bt(const unsigned short* __restrict__ A,
                        const unsigned short* __restrict__ B,
                        float* __restrict__ C,
                        int M, int N, int K, int ldc) {
  __shared__ __align__(16) unsigned short As[128 * 32];
  __shared__ __align__(16) unsigned short Bs[128 * 32];
  const int tid  = threadIdx.x;
  const int w    = tid >> 6;
  const int lane = tid & 63;
  const int wr = w >> 1, wc = w & 1;
  const int brow = blockIdx.y * 128;
  const int bcol = blockIdx.x * 128;
  const int l4 = lane >> 2;          // row within 16-row staging chunk
  const int lk = (lane & 3) * 8;     // k-element offset of this lane's 16B
  const int lhalf = lane >> 4;       // MFMA k-half selector
  const int lrow  = lane & 15;       // MFMA row/col within fragment
  const int c0 = w * 2;              // this wave's staging chunk pair

  const unsigned short* Ag0 = A + (size_t)(brow + c0 * 16 + l4) * K + lk;
  const unsigned short* Ag1 = A + (size_t)(brow + (c0 + 1) * 16 + l4) * K + lk;
  const unsigned short* Bg0 = B + (size_t)(bcol + c0 * 16 + l4) * K + lk;
  const unsigned short* Bg1 = B + (size_t)(bcol + (c0 + 1) * 16 + l4) * K + lk;
  unsigned short* lA0 = &As[c0 * 512];
  unsigned short* lA1 = &As[(c0 + 1) * 512];
  unsigned short* lB0 = &Bs[c0 * 512];
  unsigned short* lB1 = &Bs[(c0 + 1) * 512];

  f32x4 acc[4][4] = {};

  for (int k0 = 0; k0 < K; k0 += 32) {
    gload_lds16(Ag0 + k0, lA0);
    gload_lds16(Ag1 + k0, lA1);
    gload_lds16(Bg0 + k0, lB0);
    gload_lds16(Bg1 + k0, lB1);
    __syncthreads();  // drains vmcnt -> LDS tile complete
    short8 af[4], bf[4];
#pragma unroll
    for (int m = 0; m < 4; ++m)
      af[m] = *(const short8*)&As[(wr * 64 + m * 16 + lrow) * 32 + lhalf * 8];
#pragma unroll
    for (int n = 0; n < 4; ++n)
      bf[n] = *(const short8*)&Bs[(wc * 64 + n * 16 + lrow) * 32 + lhalf * 8];
#pragma unroll
    for (int m = 0; m < 4; ++m)
#pragma unroll
      for (int n = 0; n < 4; ++n)
        acc[m][n] = __builtin_amdgcn_mfma_f32_16x16x32_bf16(af[m], bf[n], acc[m][n], 0, 0, 0);
    __syncthreads();  // protect LDS before next stage
  }

  const int er = (lane >> 4) * 4;
  const int ec = lane & 15;
#pragma unroll
  for (int m = 0; m < 4; ++m)
#pragma unroll
    for (int n = 0; n < 4; ++n) {
      float* cp = C + (size_t)(brow + wr * 64 + m * 16 + er) * ldc + (bcol + wc * 64 + n * 16 + ec);
#pragma unroll
      for (int r = 0; r < 4; ++r)
        cp[(size_t)r * ldc] = acc[m][n][r];
    }
}

// ---------------- RoPE in-place on Q (cols 0..1023) and K (cols 1024..2047) of qkv(L,3072)
__global__ void rope_kernel(float* __restrict__ qkv, const float* __restrict__ fc,
                            const float* __restrict__ fs) {
  int p = blockIdx.x * blockDim.x + threadIdx.x;  // one thread per (row, pair)
  if (p >= SL * 1024) return;
  int l = p >> 10;
  int idx = p & 1023;
  int which = idx >> 9;  // 0=Q, 1=K
  int wi = idx & 511;
  int h = wi >> 5;
  int c = wi & 31;
  size_t base = (size_t)l * 3072 + which * 1024 + h * 64 + 2 * c;
  float a = qkv[base], b = qkv[base + 1];
  float cs = fc[l * 32 + c], sn = fs[l * 32 + c];
  qkv[base]     = a * cs - b * sn;
  qkv[base + 1] = a * sn + b * cs;
}

// ---------------- attention rows 1..L-1: one wave per (row, head) ----------
__global__ __launch_bounds__(256)
void attn_main(const float* __restrict__ qkv, unsigned short* __restrict__ atb) {
  int wid = blockIdx.x * 4 + (threadIdx.x >> 6);
  if (wid >= (SL - 1) * NH) return;
  int i = wid / NH + 1;  // 1..4095
  int h = wid % NH;
  int lane = threadIdx.x & 63;
  const float q = qkv[(size_t)i * 3072 + h * 64 + lane];

  // 9 candidates: t=0 -> global j=0; t=1..8 -> window j=i-8+t (valid iff j>=1)
  float sc[9];
#pragma unroll
  for (int t = 0; t < 9; ++t) {
    int j = (t == 0) ? 0 : (i - 8 + t);
    bool valid = (t == 0) || (j >= 1);
    int jc = valid ? j : 0;
    float kv = qkv[(size_t)jc * 3072 + 1024 + h * 64 + lane];
    float p = q * kv;
#pragma unroll
    for (int off = 32; off; off >>= 1) p += __shfl_xor(p, off);
    sc[t] = valid ? p * 0.125f : -1e30f;
  }
  float mx = sc[0];
#pragma unroll
  for (int t = 1; t < 9; ++t) mx = fmaxf(mx, sc[t]);
  float s = 0.f;
#pragma unroll
  for (int t = 0; t < 9; ++t) {
    float e = __expf(sc[t] - mx);
    sc[t] = e;
    s += e;
  }
  const float inv = 1.0f / s;
  float o = 0.f;
#pragma unroll
  for (int t = 0; t < 9; ++t) {
    int j = (t == 0) ? 0 : (i - 8 + t);
    bool valid = (t == 0) || (j >= 1);
    int jc = valid ? j : 0;
    o += sc[t] * qkv[(size_t)jc * 3072 + 2048 + h * 64 + lane];
  }
  atb[(size_t)i * 1024 + h * 64 + lane] = f2bf(o * inv);
}

// ---------------- attention row 0 (attends to ALL 4096 keys): 1 block/head --
__global__ __launch_bounds__(1024)
void attn_row0(const float* __restrict__ qkv, unsigned short* __restrict__ atb) {
  __shared__ float sQ[64];
  __shared__ float sS[SL];
  __shared__ float red[16];
  __shared__ float po[16][64];
  const int tid = threadIdx.x;  // 0..1023
  const int h = blockIdx.x;
  if (tid < 64) sQ[tid] = qkv[h * 64 + tid];
  __syncthreads();

  float lmax = -1e30f;
  for (int j = tid; j < SL; j += 1024) {
    const float* kr = qkv + (size_t)j * 3072 + 1024 + h * 64;
    float p = 0.f;
#pragma unroll
    for (int d = 0; d < 64; ++d) p += sQ[d] * kr[d];
    p *= 0.125f;
    sS[j] = p;
    lmax = fmaxf(lmax, p);
  }
#pragma unroll
  for (int off = 32; off; off >>= 1) lmax = fmaxf(lmax, __shfl_xor(lmax, off));
  if ((tid & 63) == 0) red[tid >> 6] = lmax;
  __syncthreads();
  float gmax = red[0];
#pragma unroll
  for (int t = 1; t < 16; ++t) gmax = fmaxf(gmax, red[t]);

  float lsum = 0.f;
  for (int j = tid; j < SL; j += 1024) {
    float e = __expf(sS[j] - gmax);
    sS[j] = e;
    lsum += e;
  }
#pragma unroll
  for (int off = 32; off; off >>= 1) lsum += __shfl_xor(lsum, off);
  __syncthreads();
  if ((tid & 63) == 0) red[tid >> 6] = lsum;
  __syncthreads();
  float gsum = 0.f;
#pragma unroll
  for (int t = 0; t < 16; ++t) gsum += red[t];
  const float inv = 1.0f / gsum;

  const int d = tid & 63, ch = tid >> 6;
  float o = 0.f;
  for (int j = ch * 256; j < ch * 256 + 256; ++j)
    o += sS[j] * qkv[(size_t)j * 3072 + 2048 + h * 64 + d];
  po[ch][d] = o;
  __syncthreads();
  if (tid < 64) {
    float t = 0.f;
#pragma unroll
    for (int c = 0; c < 16; ++c) t += po[c][tid];
    atb[h * 64 + tid] = f2bf(t * inv);
  }
}

extern "C" void kernel_launch(void* const* d_in, const int* in_sizes, int n_in,
                              void* d_out, int out_size, void* d_ws, size_t ws_size,
                              hipStream_t stream) {
  const float* x  = (const float*)d_in[0];
  const float* Wq = (const float*)d_in[1];
  const float* Wk = (const float*)d_in[2];
  const float* Wv = (const float*)d_in[3];
  const float* Wo = (const float*)d_in[4];
  const float* fc = (const float*)d_in[5];
  const float* fs = (const float*)d_in[6];
  float* out = (float*)d_out;

  char* ws = (char*)d_ws;
  unsigned short* xb  = (unsigned short*)(ws);                    // 8 MB  bf16 x
  unsigned short* w3b = (unsigned short*)(ws + ((size_t)8 << 20));  // 6 MB  bf16 [Wq;Wk;Wv]
  unsigned short* wob = (unsigned short*)(ws + ((size_t)14 << 20)); // 2 MB  bf16 Wo
  float*          qkv = (float*)(ws + ((size_t)16 << 20));          // 48 MB fp32 QKV (L,3072)
  unsigned short* atb = (unsigned short*)(ws + ((size_t)64 << 20)); // 8 MB  bf16 attn out

  const int nD4 = DM * DM / 4;
  cast4<<<(SL * DM / 4 + 255) / 256, 256, 0, stream>>>(x, xb, SL * DM / 4);
  cast4<<<(nD4 + 255) / 256, 256, 0, stream>>>(Wq, w3b, nD4);
  cast4<<<(nD4 + 255) / 256, 256, 0, stream>>>(Wk, w3b + DM * DM, nD4);
  cast4<<<(nD4 + 255) / 256, 256, 0, stream>>>(Wv, w3b + 2 * DM * DM, nD4);
  cast4<<<(nD4 + 255) / 256, 256, 0, stream>>>(Wo, wob, nD4);

  dim3 g1(3072 / 128, SL / 128);
  gemm_bt<<<g1, 256, 0, stream>>>(xb, w3b, qkv, SL, 3072, DM, 3072);

  rope_kernel<<<(SL * 1024 + 255) / 256, 256, 0, stream>>>(qkv, fc, fs);

  attn_row0<<<NH, 1024, 0, stream>>>(qkv, atb);
  attn_main<<<((SL - 1) * NH + 3) / 4, 256, 0, stream>>>(qkv, atb);

  dim3 g2(DM / 128, SL / 128);
  gemm_bt<<<g2, 256, 0, stream>>>(atb, wob, out, SL, DM, DM, DM);
}

// Round 2
// 166.839 us; speedup vs baseline: 1.1866x; 1.1866x over previous
//
#include <hip/hip_runtime.h>
#include <stdint.h>

#define SL 4096
#define DM 1024
#define NH 16
#define HDIM 64

typedef short short8 __attribute__((ext_vector_type(8)));
typedef float f32x4 __attribute__((ext_vector_type(4)));

__device__ __forceinline__ unsigned short f2bf(float f) {
  unsigned int u = __float_as_uint(f);
  u += 0x7FFF + ((u >> 16) & 1);
  return (unsigned short)(u >> 16);
}

__device__ __forceinline__ void gload_lds16(const void* g, void* l) {
  __builtin_amdgcn_global_load_lds((const __attribute__((address_space(1))) void*)g,
                                   (__attribute__((address_space(3))) void*)l, 16, 0, 0);
}

// ---------------- cast fp32 -> bf16, 4 elems/thread ----------------
__global__ void cast4(const float* __restrict__ src, unsigned short* __restrict__ dst, int n4) {
  int i = blockIdx.x * blockDim.x + threadIdx.x;
  if (i >= n4) return;
  float4 v = ((const float4*)src)[i];
  ushort4 o = make_ushort4(f2bf(v.x), f2bf(v.y), f2bf(v.z), f2bf(v.w));
  ((ushort4*)dst)[i] = o;
}

// ---------------- bf16 MFMA GEMM: C[M,N] = A[M,K] * B[N,K]^T (fp32 out) ----
// m97 structure: 128x128 tile, BK=32, 4 waves (2x2 of 64x64), global_load_lds.
__global__ void gemm_bt(const unsigned short* __restrict__ A,
                        const unsigned short* __restrict__ B,
                        float* __restrict__ C,
                        int M, int N, int K, int ldc) {
  __shared__ __align__(16) unsigned short As[128 * 32];
  __shared__ __align__(16) unsigned short Bs[128 * 32];
  const int tid  = threadIdx.x;
  const int w    = tid >> 6;
  const int lane = tid & 63;
  const int wr = w >> 1, wc = w & 1;
  const int brow = blockIdx.y * 128;
  const int bcol = blockIdx.x * 128;
  const int l4 = lane >> 2;          // row within 16-row staging chunk
  const int lk = (lane & 3) * 8;     // k-element offset of this lane's 16B
  const int lhalf = lane >> 4;       // MFMA k-half selector
  const int lrow  = lane & 15;       // MFMA row/col within fragment
  const int c0 = w * 2;              // this wave's staging chunk pair

  const unsigned short* Ag0 = A + (size_t)(brow + c0 * 16 + l4) * K + lk;
  const unsigned short* Ag1 = A + (size_t)(brow + (c0 + 1) * 16 + l4) * K + lk;
  const unsigned short* Bg0 = B + (size_t)(bcol + c0 * 16 + l4) * K + lk;
  const unsigned short* Bg1 = B + (size_t)(bcol + (c0 + 1) * 16 + l4) * K + lk;
  unsigned short* lA0 = &As[c0 * 512];
  unsigned short* lA1 = &As[(c0 + 1) * 512];
  unsigned short* lB0 = &Bs[c0 * 512];
  unsigned short* lB1 = &Bs[(c0 + 1) * 512];

  f32x4 acc[4][4] = {};

  for (int k0 = 0; k0 < K; k0 += 32) {
    gload_lds16(Ag0 + k0, lA0);
    gload_lds16(Ag1 + k0, lA1);
    gload_lds16(Bg0 + k0, lB0);
    gload_lds16(Bg1 + k0, lB1);
    __syncthreads();  // drains vmcnt -> LDS tile complete
    short8 af[4], bf[4];
#pragma unroll
    for (int m = 0; m < 4; ++m)
      af[m] = *(const short8*)&As[(wr * 64 + m * 16 + lrow) * 32 + lhalf * 8];
#pragma unroll
    for (int n = 0; n < 4; ++n)
      bf[n] = *(const short8*)&Bs[(wc * 64 + n * 16 + lrow) * 32 + lhalf * 8];
#pragma unroll
    for (int m = 0; m < 4; ++m)
#pragma unroll
      for (int n = 0; n < 4; ++n)
        acc[m][n] = __builtin_amdgcn_mfma_f32_16x16x32_bf16(af[m], bf[n], acc[m][n], 0, 0, 0);
    __syncthreads();  // protect LDS before next stage
  }

  const int er = (lane >> 4) * 4;
  const int ec = lane & 15;
#pragma unroll
  for (int m = 0; m < 4; ++m)
#pragma unroll
    for (int n = 0; n < 4; ++n) {
      float* cp = C + (size_t)(brow + wr * 64 + m * 16 + er) * ldc + (bcol + wc * 64 + n * 16 + ec);
#pragma unroll
      for (int r = 0; r < 4; ++r)
        cp[(size_t)r * ldc] = acc[m][n][r];
    }
}

// ---------------- RoPE in-place on Q (cols 0..1023) and K (cols 1024..2047) of qkv(L,3072)
__global__ void rope_kernel(float* __restrict__ qkv, const float* __restrict__ fc,
                            const float* __restrict__ fs) {
  int p = blockIdx.x * blockDim.x + threadIdx.x;  // one thread per (row, pair)
  if (p >= SL * 1024) return;
  int l = p >> 10;
  int idx = p & 1023;
  int which = idx >> 9;  // 0=Q, 1=K
  int wi = idx & 511;
  int h = wi >> 5;
  int c = wi & 31;
  size_t base = (size_t)l * 3072 + which * 1024 + h * 64 + 2 * c;
  float a = qkv[base], b = qkv[base + 1];
  float cs = fc[l * 32 + c], sn = fs[l * 32 + c];
  qkv[base]     = a * cs - b * sn;
  qkv[base + 1] = a * sn + b * cs;
}

// ---------------- attention rows 1..L-1: one wave per (row, head) ----------
__global__ __launch_bounds__(256)
void attn_main(const float* __restrict__ qkv, unsigned short* __restrict__ atb) {
  int wid = blockIdx.x * 4 + (threadIdx.x >> 6);
  if (wid >= (SL - 1) * NH) return;
  int i = wid / NH + 1;  // 1..4095
  int h = wid % NH;
  int lane = threadIdx.x & 63;
  const float q = qkv[(size_t)i * 3072 + h * 64 + lane];

  // 9 candidates: t=0 -> global j=0; t=1..8 -> window j=i-8+t (valid iff j>=1)
  float sc[9];
#pragma unroll
  for (int t = 0; t < 9; ++t) {
    int j = (t == 0) ? 0 : (i - 8 + t);
    bool valid = (t == 0) || (j >= 1);
    int jc = valid ? j : 0;
    float kv = qkv[(size_t)jc * 3072 + 1024 + h * 64 + lane];
    float p = q * kv;
#pragma unroll
    for (int off = 32; off; off >>= 1) p += __shfl_xor(p, off);
    sc[t] = valid ? p * 0.125f : -1e30f;
  }
  float mx = sc[0];
#pragma unroll
  for (int t = 1; t < 9; ++t) mx = fmaxf(mx, sc[t]);
  float s = 0.f;
#pragma unroll
  for (int t = 0; t < 9; ++t) {
    float e = __expf(sc[t] - mx);
    sc[t] = e;
    s += e;
  }
  const float inv = 1.0f / s;
  float o = 0.f;
#pragma unroll
  for (int t = 0; t < 9; ++t) {
    int j = (t == 0) ? 0 : (i - 8 + t);
    bool valid = (t == 0) || (j >= 1);
    int jc = valid ? j : 0;
    o += sc[t] * qkv[(size_t)jc * 3072 + 2048 + h * 64 + lane];
  }
  atb[(size_t)i * 1024 + h * 64 + lane] = f2bf(o * inv);
}

// ---------------- attention row 0, flash-split: 128 partials/head ----------
// grid (128, 16), block 64 (1 wave). Each wave: online softmax over 32 keys.
__global__ __launch_bounds__(64)
void attn_row0_part(const float* __restrict__ qkv, float* __restrict__ prt) {
  const int p = blockIdx.x;   // key-chunk 0..127
  const int h = blockIdx.y;   // head
  const int lane = threadIdx.x;
  const float q = qkv[h * 64 + lane];  // row 0 Q (RoPE at pos 0 is identity)
  float m = -1e30f, s = 0.f, o = 0.f;
  const int j0 = p * 32;
  for (int jj = 0; jj < 32; ++jj) {
    const int j = j0 + jj;
    float kv = qkv[(size_t)j * 3072 + 1024 + h * 64 + lane];
    float pr = q * kv;
#pragma unroll
    for (int off = 32; off; off >>= 1) pr += __shfl_xor(pr, off);
    pr *= 0.125f;
    float mn = fmaxf(m, pr);
    float c = __expf(m - mn);
    float e = __expf(pr - mn);
    float v = qkv[(size_t)j * 3072 + 2048 + h * 64 + lane];
    s = s * c + e;
    o = o * c + e * v;
    m = mn;
  }
  float* dst = prt + ((size_t)h * 128 + p) * 72;
  if (lane == 0) { dst[0] = m; dst[1] = s; }
  dst[2 + lane] = o;
}

__global__ __launch_bounds__(64)
void attn_row0_combine(const float* __restrict__ prt, unsigned short* __restrict__ atb) {
  const int h = blockIdx.x;
  const int lane = threadIdx.x;
  const float* base = prt + (size_t)h * 128 * 72;
  float M = -1e30f;
  for (int p = 0; p < 128; ++p) M = fmaxf(M, base[p * 72]);
  float s = 0.f, o = 0.f;
  for (int p = 0; p < 128; ++p) {
    float c = __expf(base[p * 72] - M);
    s += base[p * 72 + 1] * c;
    o += base[p * 72 + 2 + lane] * c;
  }
  atb[h * 64 + lane] = f2bf(o / s);
}

extern "C" void kernel_launch(void* const* d_in, const int* in_sizes, int n_in,
                              void* d_out, int out_size, void* d_ws, size_t ws_size,
                              hipStream_t stream) {
  const float* x  = (const float*)d_in[0];
  const float* Wq = (const float*)d_in[1];
  const float* Wk = (const float*)d_in[2];
  const float* Wv = (const float*)d_in[3];
  const float* Wo = (const float*)d_in[4];
  const float* fc = (const float*)d_in[5];
  const float* fs = (const float*)d_in[6];
  float* out = (float*)d_out;

  char* ws = (char*)d_ws;
  unsigned short* xb  = (unsigned short*)(ws);                      // 8 MB  bf16 x
  unsigned short* w3b = (unsigned short*)(ws + ((size_t)8 << 20));  // 6 MB  bf16 [Wq;Wk;Wv]
  unsigned short* wob = (unsigned short*)(ws + ((size_t)14 << 20)); // 2 MB  bf16 Wo
  float*          qkv = (float*)(ws + ((size_t)16 << 20));          // 48 MB fp32 QKV (L,3072)
  unsigned short* atb = (unsigned short*)(ws + ((size_t)64 << 20)); // 8 MB  bf16 attn out
  float*          prt = (float*)(ws + ((size_t)72 << 20));          // 0.6 MB row0 partials

  const int nD4 = DM * DM / 4;
  cast4<<<(SL * DM / 4 + 255) / 256, 256, 0, stream>>>(x, xb, SL * DM / 4);
  cast4<<<(nD4 + 255) / 256, 256, 0, stream>>>(Wq, w3b, nD4);
  cast4<<<(nD4 + 255) / 256, 256, 0, stream>>>(Wk, w3b + DM * DM, nD4);
  cast4<<<(nD4 + 255) / 256, 256, 0, stream>>>(Wv, w3b + 2 * DM * DM, nD4);
  cast4<<<(nD4 + 255) / 256, 256, 0, stream>>>(Wo, wob, nD4);

  dim3 g1(3072 / 128, SL / 128);
  gemm_bt<<<g1, 256, 0, stream>>>(xb, w3b, qkv, SL, 3072, DM, 3072);

  rope_kernel<<<(SL * 1024 + 255) / 256, 256, 0, stream>>>(qkv, fc, fs);

  attn_row0_part<<<dim3(128, NH), 64, 0, stream>>>(qkv, prt);
  attn_row0_combine<<<NH, 64, 0, stream>>>(prt, atb);
  attn_main<<<((SL - 1) * NH + 3) / 4, 256, 0, stream>>>(qkv, atb);

  dim3 g2(DM / 128, SL / 128);
  gemm_bt<<<g2, 256, 0, stream>>>(atb, wob, out, SL, DM, DM, DM);
}

// Round 3
// 132.739 us; speedup vs baseline: 1.4914x; 1.2569x over previous
//
#include <hip/hip_runtime.h>
#include <stdint.h>

#define SL 4096
#define DM 1024
#define NH 16
#define HDIM 64

typedef short short8 __attribute__((ext_vector_type(8)));
typedef float f32x4 __attribute__((ext_vector_type(4)));

__device__ __forceinline__ unsigned short f2bf(float f) {
  unsigned int u = __float_as_uint(f);
  u += 0x7FFF + ((u >> 16) & 1);
  return (unsigned short)(u >> 16);
}
__device__ __forceinline__ float bf2f(unsigned short u) {
  return __uint_as_float((unsigned int)u << 16);
}
__device__ __forceinline__ float bflo(unsigned int u) { return __uint_as_float(u << 16); }
__device__ __forceinline__ float bfhi(unsigned int u) { return __uint_as_float(u & 0xffff0000u); }

__device__ __forceinline__ void gload_lds16(const void* g, void* l) {
  __builtin_amdgcn_global_load_lds((const __attribute__((address_space(1))) void*)g,
                                   (__attribute__((address_space(3))) void*)l, 16, 0, 0);
}

// ---------------- cast fp32 -> bf16, 4 elems/thread ----------------
__global__ void cast4(const float* __restrict__ src, unsigned short* __restrict__ dst, int n4) {
  int i = blockIdx.x * blockDim.x + threadIdx.x;
  if (i >= n4) return;
  float4 v = ((const float4*)src)[i];
  ushort4 o = make_ushort4(f2bf(v.x), f2bf(v.y), f2bf(v.z), f2bf(v.w));
  ((ushort4*)dst)[i] = o;
}

// ---------------- bf16 MFMA GEMM: C[M,N] = A[M,K] * B[N,K]^T ----
// m97 structure: 128x128 tile, BK=32, 4 waves (2x2 of 64x64), global_load_lds.
// BF16OUT selects bf16 (ushort) or fp32 output.
template <bool BF16OUT>
__global__ void gemm_bt(const unsigned short* __restrict__ A,
                        const unsigned short* __restrict__ B,
                        void* __restrict__ Cv,
                        int M, int N, int K, int ldc) {
  __shared__ __align__(16) unsigned short As[128 * 32];
  __shared__ __align__(16) unsigned short Bs[128 * 32];
  const int tid  = threadIdx.x;
  const int w    = tid >> 6;
  const int lane = tid & 63;
  const int wr = w >> 1, wc = w & 1;
  const int brow = blockIdx.y * 128;
  const int bcol = blockIdx.x * 128;
  const int l4 = lane >> 2;
  const int lk = (lane & 3) * 8;
  const int lhalf = lane >> 4;
  const int lrow  = lane & 15;
  const int c0 = w * 2;

  const unsigned short* Ag0 = A + (size_t)(brow + c0 * 16 + l4) * K + lk;
  const unsigned short* Ag1 = A + (size_t)(brow + (c0 + 1) * 16 + l4) * K + lk;
  const unsigned short* Bg0 = B + (size_t)(bcol + c0 * 16 + l4) * K + lk;
  const unsigned short* Bg1 = B + (size_t)(bcol + (c0 + 1) * 16 + l4) * K + lk;
  unsigned short* lA0 = &As[c0 * 512];
  unsigned short* lA1 = &As[(c0 + 1) * 512];
  unsigned short* lB0 = &Bs[c0 * 512];
  unsigned short* lB1 = &Bs[(c0 + 1) * 512];

  f32x4 acc[4][4] = {};

  for (int k0 = 0; k0 < K; k0 += 32) {
    gload_lds16(Ag0 + k0, lA0);
    gload_lds16(Ag1 + k0, lA1);
    gload_lds16(Bg0 + k0, lB0);
    gload_lds16(Bg1 + k0, lB1);
    __syncthreads();
    short8 af[4], bf[4];
#pragma unroll
    for (int m = 0; m < 4; ++m)
      af[m] = *(const short8*)&As[(wr * 64 + m * 16 + lrow) * 32 + lhalf * 8];
#pragma unroll
    for (int n = 0; n < 4; ++n)
      bf[n] = *(const short8*)&Bs[(wc * 64 + n * 16 + lrow) * 32 + lhalf * 8];
#pragma unroll
    for (int m = 0; m < 4; ++m)
#pragma unroll
      for (int n = 0; n < 4; ++n)
        acc[m][n] = __builtin_amdgcn_mfma_f32_16x16x32_bf16(af[m], bf[n], acc[m][n], 0, 0, 0);
    __syncthreads();
  }

  const int er = (lane >> 4) * 4;
  const int ec = lane & 15;
#pragma unroll
  for (int m = 0; m < 4; ++m)
#pragma unroll
    for (int n = 0; n < 4; ++n) {
      const size_t roff = (size_t)(brow + wr * 64 + m * 16 + er) * ldc + (bcol + wc * 64 + n * 16 + ec);
      if constexpr (BF16OUT) {
        unsigned short* cp = (unsigned short*)Cv + roff;
#pragma unroll
        for (int r = 0; r < 4; ++r) cp[(size_t)r * ldc] = f2bf(acc[m][n][r]);
      } else {
        float* cp = (float*)Cv + roff;
#pragma unroll
        for (int r = 0; r < 4; ++r) cp[(size_t)r * ldc] = acc[m][n][r];
      }
    }
}

// ---------------- RoPE in-place on bf16 qkv: Q cols [0,1024), K cols [1024,2048)
// one thread per 4 pairs (8 contiguous elems = 16B)
__global__ void rope_bf16(unsigned short* __restrict__ qkv, const float* __restrict__ fc,
                          const float* __restrict__ fs) {
  int p = blockIdx.x * blockDim.x + threadIdx.x;
  if (p >= SL * 256) return;
  int l = p >> 8;
  int rem = p & 255;
  int which = rem >> 7;   // 0=Q, 1=K
  int wi = rem & 127;
  int h = wi >> 3;
  int g = wi & 7;         // 4-pair group within head
  unsigned short* ptr = qkv + (size_t)l * 3072 + which * 1024 + h * 64 + g * 8;
  uint4 u = *(const uint4*)ptr;
  float4 cs = *(const float4*)(fc + l * 32 + g * 4);
  float4 sn = *(const float4*)(fs + l * 32 + g * 4);
  unsigned int uu[4] = {u.x, u.y, u.z, u.w};
  float csa[4] = {cs.x, cs.y, cs.z, cs.w};
  float sna[4] = {sn.x, sn.y, sn.z, sn.w};
  unsigned int wv[4];
#pragma unroll
  for (int k = 0; k < 4; ++k) {
    float a = bflo(uu[k]), b = bfhi(uu[k]);
    float r  = a * csa[k] - b * sna[k];
    float im = a * sna[k] + b * csa[k];
    wv[k] = (unsigned int)f2bf(r) | ((unsigned int)f2bf(im) << 16);
  }
  uint4 o; o.x = wv[0]; o.y = wv[1]; o.z = wv[2]; o.w = wv[3];
  *(uint4*)ptr = o;
}

// ---------------- attention rows 1..L-1: one wave per ROW (all 16 heads) ----
// lane l: head h = l>>2, d-elements (l&3)*16 .. +15
__global__ __launch_bounds__(256)
void attn_main(const unsigned short* __restrict__ qkv, unsigned short* __restrict__ atb) {
  const int i = blockIdx.x * 4 + (threadIdx.x >> 6) + 1;
  if (i >= SL) return;
  const int lane = threadIdx.x & 63;
  const unsigned short* rowQ = qkv + (size_t)i * 3072 + lane * 16;

  float q[16];
  {
    uint4 a = *(const uint4*)rowQ;
    uint4 b = *(const uint4*)(rowQ + 8);
    unsigned int uu[8] = {a.x, a.y, a.z, a.w, b.x, b.y, b.z, b.w};
#pragma unroll
    for (int c = 0; c < 8; ++c) { q[2 * c] = bflo(uu[c]); q[2 * c + 1] = bfhi(uu[c]); }
  }

  float sc[9];
#pragma unroll
  for (int t = 0; t < 9; ++t) {
    int j = (t == 0) ? 0 : (i - 8 + t);
    bool valid = (t == 0) || (j >= 1);
    int jc = valid ? j : 0;
    const unsigned short* pk = qkv + (size_t)jc * 3072 + 1024 + lane * 16;
    uint4 a = *(const uint4*)pk;
    uint4 b = *(const uint4*)(pk + 8);
    unsigned int uu[8] = {a.x, a.y, a.z, a.w, b.x, b.y, b.z, b.w};
    float pr = 0.f;
#pragma unroll
    for (int c = 0; c < 8; ++c) pr += bflo(uu[c]) * q[2 * c] + bfhi(uu[c]) * q[2 * c + 1];
    pr += __shfl_xor(pr, 1);
    pr += __shfl_xor(pr, 2);   // 4-lane reduce: all 4 lanes of this head have the sum
    sc[t] = valid ? pr * 0.125f : -1e30f;
  }

  float mx = sc[0];
#pragma unroll
  for (int t = 1; t < 9; ++t) mx = fmaxf(mx, sc[t]);
  float s = 0.f;
#pragma unroll
  for (int t = 0; t < 9; ++t) { float e = __expf(sc[t] - mx); sc[t] = e; s += e; }
  const float inv = 1.0f / s;

  float o[16] = {};
#pragma unroll
  for (int t = 0; t < 9; ++t) {
    int j = (t == 0) ? 0 : (i - 8 + t);
    bool valid = (t == 0) || (j >= 1);
    int jc = valid ? j : 0;
    const unsigned short* pv = qkv + (size_t)jc * 3072 + 2048 + lane * 16;
    uint4 a = *(const uint4*)pv;
    uint4 b = *(const uint4*)(pv + 8);
    unsigned int uu[8] = {a.x, a.y, a.z, a.w, b.x, b.y, b.z, b.w};
#pragma unroll
    for (int c = 0; c < 8; ++c) {
      o[2 * c]     += sc[t] * bflo(uu[c]);
      o[2 * c + 1] += sc[t] * bfhi(uu[c]);
    }
  }

  unsigned int wv[8];
#pragma unroll
  for (int c = 0; c < 8; ++c)
    wv[c] = (unsigned int)f2bf(o[2 * c] * inv) | ((unsigned int)f2bf(o[2 * c + 1] * inv) << 16);
  unsigned short* po = atb + (size_t)i * 1024 + lane * 16;
  uint4 s0; s0.x = wv[0]; s0.y = wv[1]; s0.z = wv[2]; s0.w = wv[3];
  uint4 s1; s1.x = wv[4]; s1.y = wv[5]; s1.z = wv[6]; s1.w = wv[7];
  *(uint4*)po = s0;
  *(uint4*)(po + 8) = s1;
}

// ---------------- attention row 0, flash-split: 128 partials/head ----------
__global__ __launch_bounds__(64)
void attn_row0_part(const unsigned short* __restrict__ qkv, float* __restrict__ prt) {
  const int p = blockIdx.x;
  const int h = blockIdx.y;
  const int lane = threadIdx.x;
  const float q = bf2f(qkv[h * 64 + lane]);
  float m = -1e30f, s = 0.f, o = 0.f;
  const int j0 = p * 32;
  for (int jj = 0; jj < 32; ++jj) {
    const int j = j0 + jj;
    float kv = bf2f(qkv[(size_t)j * 3072 + 1024 + h * 64 + lane]);
    float pr = q * kv;
#pragma unroll
    for (int off = 32; off; off >>= 1) pr += __shfl_xor(pr, off);
    pr *= 0.125f;
    float mn = fmaxf(m, pr);
    float c = __expf(m - mn);
    float e = __expf(pr - mn);
    float v = bf2f(qkv[(size_t)j * 3072 + 2048 + h * 64 + lane]);
    s = s * c + e;
    o = o * c + e * v;
    m = mn;
  }
  float* dst = prt + ((size_t)h * 128 + p) * 72;
  if (lane == 0) { dst[0] = m; dst[1] = s; }
  dst[2 + lane] = o;
}

__global__ __launch_bounds__(64)
void attn_row0_combine(const float* __restrict__ prt, unsigned short* __restrict__ atb) {
  const int h = blockIdx.x;
  const int lane = threadIdx.x;
  const float* base = prt + (size_t)h * 128 * 72;
  float M = -1e30f;
  for (int p = 0; p < 128; ++p) M = fmaxf(M, base[p * 72]);
  float s = 0.f, o = 0.f;
  for (int p = 0; p < 128; ++p) {
    float c = __expf(base[p * 72] - M);
    s += base[p * 72 + 1] * c;
    o += base[p * 72 + 2 + lane] * c;
  }
  atb[h * 64 + lane] = f2bf(o / s);
}

extern "C" void kernel_launch(void* const* d_in, const int* in_sizes, int n_in,
                              void* d_out, int out_size, void* d_ws, size_t ws_size,
                              hipStream_t stream) {
  const float* x  = (const float*)d_in[0];
  const float* Wq = (const float*)d_in[1];
  const float* Wk = (const float*)d_in[2];
  const float* Wv = (const float*)d_in[3];
  const float* Wo = (const float*)d_in[4];
  const float* fc = (const float*)d_in[5];
  const float* fs = (const float*)d_in[6];
  float* out = (float*)d_out;

  char* ws = (char*)d_ws;
  unsigned short* xb   = (unsigned short*)(ws);                      // 8 MB  bf16 x
  unsigned short* w3b  = (unsigned short*)(ws + ((size_t)8 << 20));  // 6 MB  bf16 [Wq;Wk;Wv]
  unsigned short* wob  = (unsigned short*)(ws + ((size_t)14 << 20)); // 2 MB  bf16 Wo
  unsigned short* qkvb = (unsigned short*)(ws + ((size_t)16 << 20)); // 24 MB bf16 QKV (L,3072)
  unsigned short* atb  = (unsigned short*)(ws + ((size_t)40 << 20)); // 8 MB  bf16 attn out
  float*          prt  = (float*)(ws + ((size_t)48 << 20));          // 0.6 MB row0 partials

  const int nD4 = DM * DM / 4;
  cast4<<<(SL * DM / 4 + 255) / 256, 256, 0, stream>>>(x, xb, SL * DM / 4);
  cast4<<<(nD4 + 255) / 256, 256, 0, stream>>>(Wq, w3b, nD4);
  cast4<<<(nD4 + 255) / 256, 256, 0, stream>>>(Wk, w3b + DM * DM, nD4);
  cast4<<<(nD4 + 255) / 256, 256, 0, stream>>>(Wv, w3b + 2 * DM * DM, nD4);
  cast4<<<(nD4 + 255) / 256, 256, 0, stream>>>(Wo, wob, nD4);

  dim3 g1(3072 / 128, SL / 128);
  gemm_bt<true><<<g1, 256, 0, stream>>>(xb, w3b, (void*)qkvb, SL, 3072, DM, 3072);

  rope_bf16<<<(SL * 256 + 255) / 256, 256, 0, stream>>>(qkvb, fc, fs);

  attn_row0_part<<<dim3(128, NH), 64, 0, stream>>>(qkvb, prt);
  attn_row0_combine<<<NH, 64, 0, stream>>>(prt, atb);
  attn_main<<<(SL - 1 + 3) / 4, 256, 0, stream>>>(qkvb, atb);

  dim3 g2(DM / 128, SL / 128);
  gemm_bt<false><<<g2, 256, 0, stream>>>(atb, wob, (void*)out, SL, DM, DM, DM);
}